// Round 8
// baseline (139.987 us; speedup 1.0000x reference)
//
#include <hip/hip_runtime.h>
#include <hip/hip_bf16.h>
#include <math.h>

// Problem constants
#define B    8
#define C4   64
#define CQ   16
#define NN   512
#define L4   12
#define XSP  100          // padded LDS row stride for x (96 -> 100, bank fix)

// workspace layout (float offsets)
#define O_TH   0                                   // Thi bf16 [b][m][n]      2097152
#define O_TL   (O_TH + (size_t)B*1024*NN/2)        // Tlo bf16 [b][m][n]      2097152
#define O_FL   (O_TL + (size_t)B*1024*NN/2)        // Fl[b][q][k] fp32          65536
#define O_XXP  (O_FL + (size_t)B*CQ*NN)            // xx partials [b][q][nch]    8192
#define O_YYP  (O_XXP + (size_t)B*CQ*64)           // yy partials [b][q][nch]    8192
#define O_L2I  (O_YYP + (size_t)B*CQ*64)           // l2inv[b] (+pad to 16)        16
#define O_AH   (O_L2I + 16)                        // Ahi bf16 [b][n][k]      1048576
#define O_AL   (O_AH + (size_t)B*NN*NN/2)          // Alo bf16 [b][n][k]      1048576

// NOTE (round-4 post-mortem): do NOT split these kernels to 4-row chunks /
// grid 1024 / __launch_bounds__(256,4) — spill/traffic collapse.
// NOTE (round-6): k3 explicit double-buffer neutral (TLP covers latency).
// NOTE (round-7): dispatch elimination works (memsets folded, -3 us).
// This round: FCG scratch round-trip deleted — k12 recomputes Fc locally
// (bit-identical loop) from the x slab it already stages; wcs/bcs alias the
// t2 LDS buffers (dead until phase 1).

typedef __attribute__((ext_vector_type(8))) short short8;
typedef __attribute__((ext_vector_type(4))) float floatx4;
typedef __attribute__((ext_vector_type(16))) float floatx16;

__device__ inline void split2(float x0, float x1, uint& hw, uint& lw) {
  uint u0 = __float_as_uint(x0), u1 = __float_as_uint(x1);
  uint h0 = u0 >> 16, h1 = u1 >> 16;
  float r0 = x0 - __uint_as_float(h0 << 16);
  float r1 = x1 - __uint_as_float(h1 << 16);
  hw = h0 | (h1 << 16);
  lw = (__float_as_uint(r0) >> 16) | ((__float_as_uint(r1) >> 16) << 16);
}

// K1a: Fc = Wc x + bc -> Fl + norm partials only (FCG dump deleted).
__global__ __launch_bounds__(256) void k1a_fc(const float* __restrict__ x,
                                              const float* __restrict__ Wc,
                                              const float* __restrict__ bc,
                                              float* __restrict__ ws) {
  int id = blockIdx.x;
  int b = id & 7;
  int nch = id >> 3;
  int n0 = nch * 8;
  int t = threadIdx.x;
  __shared__ __align__(16) float xs[C4*XSP];       // [c][nl*12+j], padded
  __shared__ float wcs[CQ*65];
  __shared__ float bcs[CQ];
  __shared__ __align__(16) float fcs[8*CQ*L4];     // [nl][q][j] 1536

  for (int e = t; e < CQ*C4; e += 256) {
    int q = e >> 6, c = e & 63;
    wcs[q*65 + c] = Wc[e];
  }
  if (t < CQ) bcs[t] = bc[t];
  const float* xb = x + (size_t)b*C4*NN*L4 + (size_t)n0*L4;
  for (int f = t; f < C4*24; f += 256) {           // 24 float4s per c
    int c = f / 24, r = f - c*24;
    float4 v = *(const float4*)(xb + (size_t)c*NN*L4 + r*4);
    *(float4*)(xs + c*XSP + r*4) = v;
  }
  __syncthreads();
  // Fc: thread owns q = t&15, slots nj = (t>>4) + 16*i (i<6)
  {
    int q = t & 15, slot = t >> 4;
    float accv[6];
    #pragma unroll
    for (int i = 0; i < 6; ++i) accv[i] = bcs[q];
    for (int c = 0; c < C4; ++c) {
      float wv = wcs[q*65 + c];
      const float* xc = xs + c*XSP;
      #pragma unroll
      for (int i = 0; i < 6; ++i) accv[i] += wv * xc[slot + 16*i];
    }
    #pragma unroll
    for (int i = 0; i < 6; ++i) {
      int nj = slot + 16*i;
      int nl = nj / L4, j = nj - nl*L4;
      fcs[nl*(CQ*L4) + q*L4 + j] = accv[i];
      if (j == L4-1) ws[O_FL + ((size_t)b*CQ + q)*NN + n0 + nl] = accv[i];
    }
  }
  __syncthreads();
  if (t < CQ) {
    float yy = 0.f, xx = 0.f;
    for (int nl = 0; nl < 8; ++nl) {
      #pragma unroll
      for (int j = 0; j < L4; ++j) { float v = fcs[nl*(CQ*L4) + t*L4 + j]; yy += v*v; }
      float w = fcs[nl*(CQ*L4) + t*L4 + (L4-1)];
      xx += w*w;
    }
    // plain partial stores — every (b,q,nch) slot written, no zeroing needed
    ws[O_XXP + ((size_t)b*CQ + t)*64 + nch] = xx;
    ws[O_YYP + ((size_t)b*CQ + t)*64 + nch] = yy;
  }
}

// K12: phase 0 recomputes Fc locally (bit-identical to k1a; wcs/bcs alias
// the dead t2 buffers); phase 1 computes the T slab (TH/TL global, T2 LDS);
// phase 2 runs pass-1 MFMA and writes A planes. Side jobs: zero out,
// publish l2inv. XCD-swizzled (b = id & 7).
__global__ __launch_bounds__(256, 2) void k12_TS(const float* __restrict__ x,
                                                 const float* __restrict__ Wc,
                                                 const float* __restrict__ bc,
                                                 float* __restrict__ ws,
                                                 float* __restrict__ out) {
  int id = blockIdx.x;
  int b = id & 7;
  int nch = id >> 3;
  int n0 = nch * 8;
  int t = threadIdx.x;
  __shared__ __align__(16) float xs[C4*XSP];       // 25.6 KB
  __shared__ __align__(16) float fcs[8*CQ*L4];     // 6 KB
  __shared__ __align__(16) ushort t2h[8*1024];     // 16 KB  [nl][m]
  __shared__ __align__(16) ushort t2l[8*1024];     // 16 KB  [nl][m]
  __shared__ float l2tmp[CQ];
  // aliases: wcs/bcs live only before phase 1 overwrites t2h/t2l
  float* wcs = (float*)t2h;                        // 4160 B  <= 16 KB
  float* bcs = (float*)t2l;                        //   64 B

  // zero the output slice (2 KB/block) — replaces the memset dispatch
  if (t < 128) {
    float4 z = make_float4(0.f, 0.f, 0.f, 0.f);
    *(float4*)(out + (size_t)id*512 + t*4) = z;
  }
  for (int e = t; e < CQ*C4; e += 256) {
    int q = e >> 6, c = e & 63;
    wcs[q*65 + c] = Wc[e];
  }
  if (t < CQ) bcs[t] = bc[t];
  const float* xb = x + (size_t)b*C4*NN*L4 + (size_t)n0*L4;
  for (int f = t; f < C4*24; f += 256) {
    int c = f / 24, r = f - c*24;
    float4 v = *(const float4*)(xb + (size_t)c*NN*L4 + r*4);
    *(float4*)(xs + c*XSP + r*4) = v;
  }
  if (t < CQ) {
    const float* xp = ws + O_XXP + ((size_t)b*CQ + t)*64;
    const float* yp = ws + O_YYP + ((size_t)b*CQ + t)*64;
    float sx = 0.f, sy = 0.f;
    for (int j = 0; j < 64; ++j) { sx += xp[j]; sy += yp[j]; }
    l2tmp[t] = sqrtf(sx) * sqrtf(sy);
  }
  __syncthreads();

  // ---- phase 0: Fc recompute (exact k1a loop -> bit-identical fcs) ----
  {
    int q = t & 15, slot = t >> 4;
    float accv[6];
    #pragma unroll
    for (int i = 0; i < 6; ++i) accv[i] = bcs[q];
    for (int c = 0; c < C4; ++c) {
      float wv = wcs[q*65 + c];
      const float* xc = xs + c*XSP;
      #pragma unroll
      for (int i = 0; i < 6; ++i) accv[i] += wv * xc[slot + 16*i];
    }
    #pragma unroll
    for (int i = 0; i < 6; ++i) {
      int nj = slot + 16*i;
      int nl = nj / L4, j = nj - nl*L4;
      fcs[nl*(CQ*L4) + q*L4 + j] = accv[i];
    }
  }
  __syncthreads();   // fcs ready; wcs/bcs dead — t2h/t2l reusable below

  // ---- phase 1: T values ----
  int c = t >> 2, q0 = (t & 3) * 4;
  float vals[4][8];
  for (int nl = 0; nl < 8; ++nl) {
    float xr[L4];
    *(float4*)&xr[0] = *(const float4*)(xs + c*XSP + nl*L4);
    *(float4*)&xr[4] = *(const float4*)(xs + c*XSP + nl*L4 + 4);
    *(float4*)&xr[8] = *(const float4*)(xs + c*XSP + nl*L4 + 8);
    float tvp[4];
    #pragma unroll
    for (int i = 0; i < 4; ++i) {
      const float* fq = fcs + nl*(CQ*L4) + (q0+i)*L4;
      float a = 0.f;
      #pragma unroll
      for (int j = 0; j < L4; ++j) a += fq[j] * xr[j];
      tvp[i] = a;
      vals[i][nl] = a;
    }
    uint hw0, lw0, hw1, lw1;
    split2(tvp[0], tvp[1], hw0, lw0);
    split2(tvp[2], tvp[3], hw1, lw1);
    // T2 slab into LDS: m = c*16 + q0 + {0..3}; byte addr = t*8 within row
    *(uint2*)(t2h + nl*1024 + t*4) = make_uint2(hw0, hw1);
    *(uint2*)(t2l + nl*1024 + t*4) = make_uint2(lw0, lw1);
  }
  ushort* TH = (ushort*)(ws + O_TH);
  ushort* TL = (ushort*)(ws + O_TL);
  #pragma unroll
  for (int i = 0; i < 4; ++i) {
    int m = c*16 + q0 + i;
    uint hw[4], lw[4];
    #pragma unroll
    for (int jj = 0; jj < 4; ++jj)
      split2(vals[i][2*jj], vals[i][2*jj+1], hw[jj], lw[jj]);
    size_t off = ((size_t)b*1024 + m)*NN + n0;
    *(uint4*)(TH + off) = make_uint4(hw[0], hw[1], hw[2], hw[3]);
    *(uint4*)(TL + off) = make_uint4(lw[0], lw[1], lw[2], lw[3]);
  }
  __syncthreads();

  // ---- phase 2: pass-1 MFMA over the LDS T2 slab ----
  float l2sum = 0.f;
  #pragma unroll
  for (int q = 0; q < CQ; ++q) l2sum += l2tmp[q];
  float l2inv = 1.0f / l2sum;
  if (nch == 0 && t == 0) ws[O_L2I + b] = l2inv;   // publish for k3

  int w = t >> 6, lane = t & 63;
  int col = lane & 31, half = lane >> 5;
  const float* flb = ws + O_FL + (size_t)b*CQ*NN;
  short8 bhf[4], blf[4];
  int kcol[4];
  #pragma unroll
  for (int kt = 0; kt < 4; ++kt) {
    kcol[kt] = w*128 + kt*32 + col;
    float f[8];
    #pragma unroll
    for (int e = 0; e < 8; ++e) f[e] = flb[(size_t)(half*8 + e)*NN + kcol[kt]];
    #pragma unroll
    for (int p = 0; p < 4; ++p) {
      uint hw, lw;
      split2(f[2*p], f[2*p+1], hw, lw);
      ((uint*)&bhf[kt])[p] = hw;
      ((uint*)&blf[kt])[p] = lw;
    }
  }
  ushort* AH = (ushort*)(ws + O_AH) + ((size_t)b*NN + n0)*NN;
  ushort* AL = (ushort*)(ws + O_AL) + ((size_t)b*NN + n0)*NN;

  for (int i = 0; i < 8; ++i) {
    short8 ah[2], al[2];
    #pragma unroll
    for (int ct = 0; ct < 2; ++ct) {
      int off = i*1024 + (ct*32 + col)*16 + half*8;
      ah[ct] = *(const short8*)(t2h + off);
      al[ct] = *(const short8*)(t2l + off);
    }
    #pragma unroll
    for (int kt = 0; kt < 4; ++kt) {
      floatx16 acc[2];
      #pragma unroll
      for (int ct = 0; ct < 2; ++ct) {
        floatx16 a = {0.f,0.f,0.f,0.f,0.f,0.f,0.f,0.f,
                      0.f,0.f,0.f,0.f,0.f,0.f,0.f,0.f};
        a = __builtin_amdgcn_mfma_f32_32x32x16_bf16(ah[ct], bhf[kt], a, 0, 0, 0);
        a = __builtin_amdgcn_mfma_f32_32x32x16_bf16(ah[ct], blf[kt], a, 0, 0, 0);
        a = __builtin_amdgcn_mfma_f32_32x32x16_bf16(al[ct], bhf[kt], a, 0, 0, 0);
        acc[ct] = a;
      }
      float m = acc[0][0];
      #pragma unroll
      for (int ct = 0; ct < 2; ++ct)
        #pragma unroll
        for (int rg = 0; rg < 16; ++rg)
          if (ct + rg) m = fmaxf(m, acc[ct][rg]);
      m = fmaxf(m, __shfl_xor(m, 32));
      // relu(tanh(x)) == tanh(relu(x)); tanh(x>=0) = 1 - 2/(e^{2x}+1)
      float xp = fmaxf(m * l2inv, 0.f);
      float av = 1.f - __fdividef(2.f, __expf(2.f * xp) + 1.f);
      uint u = __float_as_uint(av);
      uint hh = u >> 16;
      float r = av - __uint_as_float(hh << 16);
      ushort lv = (ushort)(__float_as_uint(r) >> 16);
      if (half == 0) {
        AH[(size_t)i*NN + kcol[kt]] = (ushort)hh;
        AL[(size_t)i*NN + kcol[kt]] = lv;
      }
    }
  }
}

// K3 (pass 2, MFMA split-bf16) with fused output GEMM. Double-buffered
// async staging; l2inv read as one scalar from k12.
__global__ __launch_bounds__(256, 2) void k3_mfma(const float* __restrict__ Wg,
                                                  const float* __restrict__ bg,
                                                  float* __restrict__ ws,
                                                  float* __restrict__ out) {
  int id = blockIdx.x;             // (mbb*8 + kb)*8 + b
  int b = id & 7;
  int rest = id >> 3;
  int kb = rest & 7;
  int mbb = rest >> 3;
  int t = threadIdx.x;
  int lane = t & 63;
  int w = t >> 6;
  int mw = w >> 1, kw = w & 1;
  int row = lane & 15, quad = lane >> 4;

  __shared__ __align__(16) ushort Ah[2][128*32];   // 16 KB
  __shared__ __align__(16) ushort Al[2][128*32];   // 16 KB
  __shared__ __align__(16) ushort Bh[2][64*32];    // 8 KB
  __shared__ __align__(16) ushort Bl[2][64*32];    // 8 KB
  __shared__ float wgs[C4*8];       // Wg[o][c-slice]
  __shared__ float xg_s[8][64];     // xg slice [c-local][k-local]

  float l2inv = ws[O_L2I + b];
  for (int e = t; e < C4*8; e += 256) {
    int o = e >> 3, cl = e & 7;
    wgs[e] = Wg[o*C4 + mbb*8 + cl];
  }

  const ushort* TH = (const ushort*)(ws + O_TH) + ((size_t)b*1024 + mbb*128)*NN;
  const ushort* TL = (const ushort*)(ws + O_TL) + ((size_t)b*1024 + mbb*128)*NN;
  const ushort* AHp = (const ushort*)(ws + O_AH) + ((size_t)b*NN + kb*64)*NN;
  const ushort* ALp = (const ushort*)(ws + O_AL) + ((size_t)b*NN + kb*64)*NN;

  // staging geometry: lds ushort offset f*8 == (f>>2)*32 + (f&3)*8 (linear)
  const int mA0 = t >> 2,        sA0 = (t & 3) * 8;
  const int mA1 = (t + 256) >> 2, sA1 = (t & 3) * 8;   // (t+256)&3 == t&3
  const int jB  = t >> 2,        sB  = (t & 3) * 8;

  uint4 rah0, rah1, ral0, ral1, rbh, rbl;              // named regs (no arrays)
  #define K3_LOAD(p0)                                                    \
    rah0 = *(const uint4*)(TH + (size_t)mA0*NN + (p0) + sA0);            \
    rah1 = *(const uint4*)(TH + (size_t)mA1*NN + (p0) + sA1);            \
    ral0 = *(const uint4*)(TL + (size_t)mA0*NN + (p0) + sA0);            \
    ral1 = *(const uint4*)(TL + (size_t)mA1*NN + (p0) + sA1);            \
    rbh  = *(const uint4*)(AHp + (size_t)jB*NN + (p0) + sB);             \
    rbl  = *(const uint4*)(ALp + (size_t)jB*NN + (p0) + sB);
  #define K3_WRITE(buf)                                                  \
    *(uint4*)(&Ah[buf][t*8])         = rah0;                             \
    *(uint4*)(&Ah[buf][(t+256)*8])   = rah1;                             \
    *(uint4*)(&Al[buf][t*8])         = ral0;                             \
    *(uint4*)(&Al[buf][(t+256)*8])   = ral1;                             \
    *(uint4*)(&Bh[buf][t*8])         = rbh;                              \
    *(uint4*)(&Bl[buf][t*8])         = rbl;

  floatx4 acc[4][2];
  #pragma unroll
  for (int i = 0; i < 4; ++i)
    #pragma unroll
    for (int j = 0; j < 2; ++j) acc[i][j] = (floatx4){0.f, 0.f, 0.f, 0.f};

  // prologue: stage tile 0 into buffer 0
  K3_LOAD(0)
  K3_WRITE(0)
  __syncthreads();

  int cur = 0;
  for (int ksx = 0; ksx < 16; ++ksx) {
    if (ksx < 15) { K3_LOAD((ksx+1)*32) }   // issue next-tile loads early
    // compute tile ksx from buf[cur]
    short8 bh[2], bl[2];
    #pragma unroll
    for (int kt = 0; kt < 2; ++kt) {
      int jrow = kw*32 + kt*16 + row;
      bh[kt] = *(const short8*)(&Bh[cur][jrow*32 + quad*8]);
      bl[kt] = *(const short8*)(&Bl[cur][jrow*32 + quad*8]);
    }
    #pragma unroll
    for (int mt = 0; mt < 4; ++mt) {
      int mrow = mw*64 + mt*16 + row;
      short8 ah = *(const short8*)(&Ah[cur][mrow*32 + quad*8]);
      short8 al = *(const short8*)(&Al[cur][mrow*32 + quad*8]);
      #pragma unroll
      for (int kt = 0; kt < 2; ++kt) {
        acc[mt][kt] = __builtin_amdgcn_mfma_f32_16x16x32_bf16(ah, bh[kt], acc[mt][kt], 0, 0, 0);
        acc[mt][kt] = __builtin_amdgcn_mfma_f32_16x16x32_bf16(ah, bl[kt], acc[mt][kt], 0, 0, 0);
        acc[mt][kt] = __builtin_amdgcn_mfma_f32_16x16x32_bf16(al, bh[kt], acc[mt][kt], 0, 0, 0);
      }
    }
    if (ksx < 15) {
      K3_WRITE(cur ^ 1)       // load latency was hidden under the MFMAs above
      __syncthreads();        // single barrier per K-step
      cur ^= 1;
    }
  }

  const float* flb = ws + O_FL + (size_t)b*CQ*NN;
  float fl[2][4];
  #pragma unroll
  for (int kt = 0; kt < 2; ++kt) {
    int kcol = kb*64 + kw*32 + kt*16 + row;
    #pragma unroll
    for (int rg = 0; rg < 4; ++rg)
      fl[kt][rg] = flb[(size_t)(quad*4 + rg)*NN + kcol];
  }
  #pragma unroll
  for (int mt = 0; mt < 4; ++mt) {
    #pragma unroll
    for (int kt = 0; kt < 2; ++kt) {
      float s = fl[kt][0]*acc[mt][kt][0] + fl[kt][1]*acc[mt][kt][1]
              + fl[kt][2]*acc[mt][kt][2] + fl[kt][3]*acc[mt][kt][3];
      s += __shfl_xor(s, 32);
      s += __shfl_xor(s, 16);
      if (quad == 0)
        xg_s[mw*4 + mt][kw*32 + kt*16 + row] = s * l2inv;
    }
  }
  __syncthreads();
  // mini-GEMM: Fg partial = Wg[:, c-slice] * xg_s, atomic into out
  int kl = t & 63, og = t >> 6;
  #pragma unroll
  for (int oi = 0; oi < 16; ++oi) {
    int o = og*16 + oi;
    float a = 0.f;
    #pragma unroll
    for (int cl = 0; cl < 8; ++cl) a += wgs[o*8 + cl] * xg_s[cl][kl];
    if (mbb == 0) a += bg[o];
    atomicAdd(out + ((size_t)(b*C4 + o))*NN + kb*64 + kl, a);
  }
}

extern "C" void kernel_launch(void* const* d_in, const int* in_sizes, int n_in,
                              void* d_out, int out_size, void* d_ws, size_t ws_size,
                              hipStream_t stream) {
  const float* x  = (const float*)d_in[0];
  const float* Wc = (const float*)d_in[1];
  const float* bc = (const float*)d_in[2];
  const float* Wg = (const float*)d_in[3];
  const float* bg = (const float*)d_in[4];
  float* ws  = (float*)d_ws;
  float* out = (float*)d_out;

  // 3 dispatches, no memsets, no FCG scratch round-trip.
  k1a_fc <<<B*64, 256, 0, stream>>>(x, Wc, bc, ws);
  k12_TS <<<B*64, 256, 0, stream>>>(x, Wc, bc, ws, out);
  k3_mfma<<<B*64, 256, 0, stream>>>(Wg, bg, ws, out);
}

// Round 9
// 136.225 us; speedup vs baseline: 1.0276x; 1.0276x over previous
//
#include <hip/hip_runtime.h>
#include <hip/hip_bf16.h>
#include <math.h>

// Problem constants
#define B    8
#define C4   64
#define CQ   16
#define NN   512
#define L4   12
#define XSP  100          // padded LDS row stride for x (96 -> 100, bank fix)

// workspace layout (float offsets)
#define O_TH   0                                   // Thi bf16 [b][m][n]      2097152
#define O_TL   (O_TH + (size_t)B*1024*NN/2)        // Tlo bf16 [b][m][n]      2097152
#define O_FL   (O_TL + (size_t)B*1024*NN/2)        // Fl[b][q][k] fp32          65536
#define O_XXP  (O_FL + (size_t)B*CQ*NN)            // xx partials [b][q][nch]    8192
#define O_YYP  (O_XXP + (size_t)B*CQ*64)           // yy partials [b][q][nch]    8192
#define O_L2I  (O_YYP + (size_t)B*CQ*64)           // l2inv[b] (+pad to 16)        16
#define O_AH   (O_L2I + 16)                        // Ahi bf16 [b][n][k]      1048576
#define O_AL   (O_AH + (size_t)B*NN*NN/2)          // Alo bf16 [b][n][k]      1048576
#define O_FCG  (O_AL + (size_t)B*NN*NN/2)          // Fc scratch [blk][1536]   786432

// SESSION LEDGER (what's proven on this problem):
//  r1: merging Fc-compute into T kernel -> VGPR=64 spill collapse (5x). NO.
//  r2: k1t+k2 merge, T2 planes LDS-only (-33 MB round-trip): -5.5 us. YES.
//  r4: 4-row chunks / grid 1024 / bounds(256,4): spill+RFO collapse. NO.
//  r6: k3 explicit double-buffer: neutral (TLP already covers latency).
//  r7: dispatch elimination (memsets folded, atomics->partials): -3 us. YES.
//  r8: FCG round-trip deletion via k12 Fc-recompute: +3.8 us (serial
//      phase-0 on critical path beats 3 MB L2 traffic). REVERTED.
// This file == round-7 champion (136.2 us verified).

typedef __attribute__((ext_vector_type(8))) short short8;
typedef __attribute__((ext_vector_type(4))) float floatx4;
typedef __attribute__((ext_vector_type(16))) float floatx16;

__device__ inline void split2(float x0, float x1, uint& hw, uint& lw) {
  uint u0 = __float_as_uint(x0), u1 = __float_as_uint(x1);
  uint h0 = u0 >> 16, h1 = u1 >> 16;
  float r0 = x0 - __uint_as_float(h0 << 16);
  float r1 = x1 - __uint_as_float(h1 << 16);
  hw = h0 | (h1 << 16);
  lw = (__float_as_uint(r0) >> 16) | ((__float_as_uint(r1) >> 16) << 16);
}

// K1a: Fc = Wc x + bc, Fl, norm PARTIALS (plain stores, no atomics/memset);
// Fc -> global scratch. XCD-swizzled.
__global__ __launch_bounds__(256) void k1a_fc(const float* __restrict__ x,
                                              const float* __restrict__ Wc,
                                              const float* __restrict__ bc,
                                              float* __restrict__ ws) {
  int id = blockIdx.x;
  int b = id & 7;
  int nch = id >> 3;
  int n0 = nch * 8;
  int t = threadIdx.x;
  __shared__ __align__(16) float xs[C4*XSP];       // [c][nl*12+j], padded
  __shared__ float wcs[CQ*65];
  __shared__ float bcs[CQ];
  __shared__ __align__(16) float fcs[8*CQ*L4];     // [nl][q][j] 1536

  for (int e = t; e < CQ*C4; e += 256) {
    int q = e >> 6, c = e & 63;
    wcs[q*65 + c] = Wc[e];
  }
  if (t < CQ) bcs[t] = bc[t];
  const float* xb = x + (size_t)b*C4*NN*L4 + (size_t)n0*L4;
  for (int f = t; f < C4*24; f += 256) {           // 24 float4s per c
    int c = f / 24, r = f - c*24;
    float4 v = *(const float4*)(xb + (size_t)c*NN*L4 + r*4);
    *(float4*)(xs + c*XSP + r*4) = v;
  }
  __syncthreads();
  // Fc: thread owns q = t&15, slots nj = (t>>4) + 16*i (i<6)
  {
    int q = t & 15, slot = t >> 4;
    float accv[6];
    #pragma unroll
    for (int i = 0; i < 6; ++i) accv[i] = bcs[q];
    for (int c = 0; c < C4; ++c) {
      float wv = wcs[q*65 + c];
      const float* xc = xs + c*XSP;
      #pragma unroll
      for (int i = 0; i < 6; ++i) accv[i] += wv * xc[slot + 16*i];
    }
    #pragma unroll
    for (int i = 0; i < 6; ++i) {
      int nj = slot + 16*i;
      int nl = nj / L4, j = nj - nl*L4;
      fcs[nl*(CQ*L4) + q*L4 + j] = accv[i];
      if (j == L4-1) ws[O_FL + ((size_t)b*CQ + q)*NN + n0 + nl] = accv[i];
    }
  }
  __syncthreads();
  if (t < CQ) {
    float yy = 0.f, xx = 0.f;
    for (int nl = 0; nl < 8; ++nl) {
      #pragma unroll
      for (int j = 0; j < L4; ++j) { float v = fcs[nl*(CQ*L4) + t*L4 + j]; yy += v*v; }
      float w = fcs[nl*(CQ*L4) + t*L4 + (L4-1)];
      xx += w*w;
    }
    // plain partial stores — every (b,q,nch) slot written, no zeroing needed
    ws[O_XXP + ((size_t)b*CQ + t)*64 + nch] = xx;
    ws[O_YYP + ((size_t)b*CQ + t)*64 + nch] = yy;
  }
  // dump Fc to global scratch (contiguous)
  float* fcg = ws + O_FCG + (size_t)(b*64 + nch)*1536;
  for (int f = t; f < 384; f += 256)
    *(float4*)(fcg + f*4) = *(const float4*)(fcs + f*4);
}

// K12 (merged k1t+k2): phase 1 computes the T slab for 8 n-rows, writing
// TH/TL (k3 input) to global and the T2 slab ONLY into LDS; phase 2 runs
// the pass-1 MFMA (all 512 k per block) on the LDS slab and writes A planes.
// Side jobs: zero `out` (replaces memset dispatch), publish l2inv[b].
__global__ __launch_bounds__(256, 2) void k12_TS(const float* __restrict__ x,
                                                 float* __restrict__ ws,
                                                 float* __restrict__ out) {
  int id = blockIdx.x;
  int b = id & 7;
  int nch = id >> 3;
  int n0 = nch * 8;
  int t = threadIdx.x;
  __shared__ __align__(16) float xs[C4*XSP];       // 25.6 KB
  __shared__ __align__(16) float fcs[8*CQ*L4];     // 6 KB
  __shared__ __align__(16) ushort t2h[8*1024];     // 16 KB  [nl][m]
  __shared__ __align__(16) ushort t2l[8*1024];     // 16 KB  [nl][m]
  __shared__ float l2tmp[CQ];

  // zero the output slice (2 KB/block) — replaces the memset dispatch;
  // k12 strictly precedes k3, so out is zeroed before any atomicAdd.
  if (t < 128) {
    float4 z = make_float4(0.f, 0.f, 0.f, 0.f);
    *(float4*)(out + (size_t)id*512 + t*4) = z;
  }
  const float* xb = x + (size_t)b*C4*NN*L4 + (size_t)n0*L4;
  for (int f = t; f < C4*24; f += 256) {
    int c = f / 24, r = f - c*24;
    float4 v = *(const float4*)(xb + (size_t)c*NN*L4 + r*4);
    *(float4*)(xs + c*XSP + r*4) = v;
  }
  {
    const float* fcg = ws + O_FCG + (size_t)(b*64 + nch)*1536;
    for (int f = t; f < 384; f += 256)
      *(float4*)(fcs + f*4) = *(const float4*)(fcg + f*4);
  }
  if (t < CQ) {
    const float* xp = ws + O_XXP + ((size_t)b*CQ + t)*64;
    const float* yp = ws + O_YYP + ((size_t)b*CQ + t)*64;
    float sx = 0.f, sy = 0.f;
    for (int j = 0; j < 64; ++j) { sx += xp[j]; sy += yp[j]; }
    l2tmp[t] = sqrtf(sx) * sqrtf(sy);
  }
  __syncthreads();

  // ---- phase 1: T values (identical math to k1t) ----
  int c = t >> 2, q0 = (t & 3) * 4;
  float vals[4][8];
  for (int nl = 0; nl < 8; ++nl) {
    float xr[L4];
    *(float4*)&xr[0] = *(const float4*)(xs + c*XSP + nl*L4);
    *(float4*)&xr[4] = *(const float4*)(xs + c*XSP + nl*L4 + 4);
    *(float4*)&xr[8] = *(const float4*)(xs + c*XSP + nl*L4 + 8);
    float tvp[4];
    #pragma unroll
    for (int i = 0; i < 4; ++i) {
      const float* fq = fcs + nl*(CQ*L4) + (q0+i)*L4;
      float a = 0.f;
      #pragma unroll
      for (int j = 0; j < L4; ++j) a += fq[j] * xr[j];
      tvp[i] = a;
      vals[i][nl] = a;
    }
    uint hw0, lw0, hw1, lw1;
    split2(tvp[0], tvp[1], hw0, lw0);
    split2(tvp[2], tvp[3], hw1, lw1);
    // T2 slab into LDS: m = c*16 + q0 + {0..3}; byte addr = t*8 within row
    *(uint2*)(t2h + nl*1024 + t*4) = make_uint2(hw0, hw1);
    *(uint2*)(t2l + nl*1024 + t*4) = make_uint2(lw0, lw1);
  }
  ushort* TH = (ushort*)(ws + O_TH);
  ushort* TL = (ushort*)(ws + O_TL);
  #pragma unroll
  for (int i = 0; i < 4; ++i) {
    int m = c*16 + q0 + i;
    uint hw[4], lw[4];
    #pragma unroll
    for (int jj = 0; jj < 4; ++jj)
      split2(vals[i][2*jj], vals[i][2*jj+1], hw[jj], lw[jj]);
    size_t off = ((size_t)b*1024 + m)*NN + n0;
    *(uint4*)(TH + off) = make_uint4(hw[0], hw[1], hw[2], hw[3]);
    *(uint4*)(TL + off) = make_uint4(lw[0], lw[1], lw[2], lw[3]);
  }
  __syncthreads();

  // ---- phase 2: pass-1 MFMA over the LDS T2 slab ----
  float l2sum = 0.f;
  #pragma unroll
  for (int q = 0; q < CQ; ++q) l2sum += l2tmp[q];
  float l2inv = 1.0f / l2sum;
  if (nch == 0 && t == 0) ws[O_L2I + b] = l2inv;   // publish for k3

  int w = t >> 6, lane = t & 63;
  int col = lane & 31, half = lane >> 5;
  const float* flb = ws + O_FL + (size_t)b*CQ*NN;
  short8 bhf[4], blf[4];
  int kcol[4];
  #pragma unroll
  for (int kt = 0; kt < 4; ++kt) {
    kcol[kt] = w*128 + kt*32 + col;
    float f[8];
    #pragma unroll
    for (int e = 0; e < 8; ++e) f[e] = flb[(size_t)(half*8 + e)*NN + kcol[kt]];
    #pragma unroll
    for (int p = 0; p < 4; ++p) {
      uint hw, lw;
      split2(f[2*p], f[2*p+1], hw, lw);
      ((uint*)&bhf[kt])[p] = hw;
      ((uint*)&blf[kt])[p] = lw;
    }
  }
  ushort* AH = (ushort*)(ws + O_AH) + ((size_t)b*NN + n0)*NN;
  ushort* AL = (ushort*)(ws + O_AL) + ((size_t)b*NN + n0)*NN;

  for (int i = 0; i < 8; ++i) {
    short8 ah[2], al[2];
    #pragma unroll
    for (int ct = 0; ct < 2; ++ct) {
      int off = i*1024 + (ct*32 + col)*16 + half*8;
      ah[ct] = *(const short8*)(t2h + off);
      al[ct] = *(const short8*)(t2l + off);
    }
    #pragma unroll
    for (int kt = 0; kt < 4; ++kt) {
      floatx16 acc[2];
      #pragma unroll
      for (int ct = 0; ct < 2; ++ct) {
        floatx16 a = {0.f,0.f,0.f,0.f,0.f,0.f,0.f,0.f,
                      0.f,0.f,0.f,0.f,0.f,0.f,0.f,0.f};
        a = __builtin_amdgcn_mfma_f32_32x32x16_bf16(ah[ct], bhf[kt], a, 0, 0, 0);
        a = __builtin_amdgcn_mfma_f32_32x32x16_bf16(ah[ct], blf[kt], a, 0, 0, 0);
        a = __builtin_amdgcn_mfma_f32_32x32x16_bf16(al[ct], bhf[kt], a, 0, 0, 0);
        acc[ct] = a;
      }
      float m = acc[0][0];
      #pragma unroll
      for (int ct = 0; ct < 2; ++ct)
        #pragma unroll
        for (int rg = 0; rg < 16; ++rg)
          if (ct + rg) m = fmaxf(m, acc[ct][rg]);
      m = fmaxf(m, __shfl_xor(m, 32));
      // relu(tanh(x)) == tanh(relu(x)); tanh(x>=0) = 1 - 2/(e^{2x}+1)
      float xp = fmaxf(m * l2inv, 0.f);
      float av = 1.f - __fdividef(2.f, __expf(2.f * xp) + 1.f);
      uint u = __float_as_uint(av);
      uint hh = u >> 16;
      float r = av - __uint_as_float(hh << 16);
      ushort lv = (ushort)(__float_as_uint(r) >> 16);
      if (half == 0) {
        AH[(size_t)i*NN + kcol[kt]] = (ushort)hh;
        AL[(size_t)i*NN + kcol[kt]] = lv;
      }
    }
  }
}

// K3 (pass 2, MFMA split-bf16) with fused output GEMM. Double-buffered
// async staging (neutral but kept); l2inv read as one scalar from k12.
__global__ __launch_bounds__(256, 2) void k3_mfma(const float* __restrict__ Wg,
                                                  const float* __restrict__ bg,
                                                  float* __restrict__ ws,
                                                  float* __restrict__ out) {
  int id = blockIdx.x;             // (mbb*8 + kb)*8 + b
  int b = id & 7;
  int rest = id >> 3;
  int kb = rest & 7;
  int mbb = rest >> 3;
  int t = threadIdx.x;
  int lane = t & 63;
  int w = t >> 6;
  int mw = w >> 1, kw = w & 1;
  int row = lane & 15, quad = lane >> 4;

  __shared__ __align__(16) ushort Ah[2][128*32];   // 16 KB
  __shared__ __align__(16) ushort Al[2][128*32];   // 16 KB
  __shared__ __align__(16) ushort Bh[2][64*32];    // 8 KB
  __shared__ __align__(16) ushort Bl[2][64*32];    // 8 KB
  __shared__ float wgs[C4*8];       // Wg[o][c-slice]
  __shared__ float xg_s[8][64];     // xg slice [c-local][k-local]

  float l2inv = ws[O_L2I + b];
  for (int e = t; e < C4*8; e += 256) {
    int o = e >> 3, cl = e & 7;
    wgs[e] = Wg[o*C4 + mbb*8 + cl];
  }

  const ushort* TH = (const ushort*)(ws + O_TH) + ((size_t)b*1024 + mbb*128)*NN;
  const ushort* TL = (const ushort*)(ws + O_TL) + ((size_t)b*1024 + mbb*128)*NN;
  const ushort* AHp = (const ushort*)(ws + O_AH) + ((size_t)b*NN + kb*64)*NN;
  const ushort* ALp = (const ushort*)(ws + O_AL) + ((size_t)b*NN + kb*64)*NN;

  // staging geometry: lds ushort offset f*8 == (f>>2)*32 + (f&3)*8 (linear)
  const int mA0 = t >> 2,        sA0 = (t & 3) * 8;
  const int mA1 = (t + 256) >> 2, sA1 = (t & 3) * 8;   // (t+256)&3 == t&3
  const int jB  = t >> 2,        sB  = (t & 3) * 8;

  uint4 rah0, rah1, ral0, ral1, rbh, rbl;              // named regs (no arrays)
  #define K3_LOAD(p0)                                                    \
    rah0 = *(const uint4*)(TH + (size_t)mA0*NN + (p0) + sA0);            \
    rah1 = *(const uint4*)(TH + (size_t)mA1*NN + (p0) + sA1);            \
    ral0 = *(const uint4*)(TL + (size_t)mA0*NN + (p0) + sA0);            \
    ral1 = *(const uint4*)(TL + (size_t)mA1*NN + (p0) + sA1);            \
    rbh  = *(const uint4*)(AHp + (size_t)jB*NN + (p0) + sB);             \
    rbl  = *(const uint4*)(ALp + (size_t)jB*NN + (p0) + sB);
  #define K3_WRITE(buf)                                                  \
    *(uint4*)(&Ah[buf][t*8])         = rah0;                             \
    *(uint4*)(&Ah[buf][(t+256)*8])   = rah1;                             \
    *(uint4*)(&Al[buf][t*8])         = ral0;                             \
    *(uint4*)(&Al[buf][(t+256)*8])   = ral1;                             \
    *(uint4*)(&Bh[buf][t*8])         = rbh;                              \
    *(uint4*)(&Bl[buf][t*8])         = rbl;

  floatx4 acc[4][2];
  #pragma unroll
  for (int i = 0; i < 4; ++i)
    #pragma unroll
    for (int j = 0; j < 2; ++j) acc[i][j] = (floatx4){0.f, 0.f, 0.f, 0.f};

  // prologue: stage tile 0 into buffer 0
  K3_LOAD(0)
  K3_WRITE(0)
  __syncthreads();

  int cur = 0;
  for (int ksx = 0; ksx < 16; ++ksx) {
    if (ksx < 15) { K3_LOAD((ksx+1)*32) }   // issue next-tile loads early
    // compute tile ksx from buf[cur]
    short8 bh[2], bl[2];
    #pragma unroll
    for (int kt = 0; kt < 2; ++kt) {
      int jrow = kw*32 + kt*16 + row;
      bh[kt] = *(const short8*)(&Bh[cur][jrow*32 + quad*8]);
      bl[kt] = *(const short8*)(&Bl[cur][jrow*32 + quad*8]);
    }
    #pragma unroll
    for (int mt = 0; mt < 4; ++mt) {
      int mrow = mw*64 + mt*16 + row;
      short8 ah = *(const short8*)(&Ah[cur][mrow*32 + quad*8]);
      short8 al = *(const short8*)(&Al[cur][mrow*32 + quad*8]);
      #pragma unroll
      for (int kt = 0; kt < 2; ++kt) {
        acc[mt][kt] = __builtin_amdgcn_mfma_f32_16x16x32_bf16(ah, bh[kt], acc[mt][kt], 0, 0, 0);
        acc[mt][kt] = __builtin_amdgcn_mfma_f32_16x16x32_bf16(ah, bl[kt], acc[mt][kt], 0, 0, 0);
        acc[mt][kt] = __builtin_amdgcn_mfma_f32_16x16x32_bf16(al, bh[kt], acc[mt][kt], 0, 0, 0);
      }
    }
    if (ksx < 15) {
      K3_WRITE(cur ^ 1)       // load latency was hidden under the MFMAs above
      __syncthreads();        // single barrier per K-step
      cur ^= 1;
    }
  }

  const float* flb = ws + O_FL + (size_t)b*CQ*NN;
  float fl[2][4];
  #pragma unroll
  for (int kt = 0; kt < 2; ++kt) {
    int kcol = kb*64 + kw*32 + kt*16 + row;
    #pragma unroll
    for (int rg = 0; rg < 4; ++rg)
      fl[kt][rg] = flb[(size_t)(quad*4 + rg)*NN + kcol];
  }
  #pragma unroll
  for (int mt = 0; mt < 4; ++mt) {
    #pragma unroll
    for (int kt = 0; kt < 2; ++kt) {
      float s = fl[kt][0]*acc[mt][kt][0] + fl[kt][1]*acc[mt][kt][1]
              + fl[kt][2]*acc[mt][kt][2] + fl[kt][3]*acc[mt][kt][3];
      s += __shfl_xor(s, 32);
      s += __shfl_xor(s, 16);
      if (quad == 0)
        xg_s[mw*4 + mt][kw*32 + kt*16 + row] = s * l2inv;
    }
  }
  __syncthreads();
  // mini-GEMM: Fg partial = Wg[:, c-slice] * xg_s, atomic into out
  int kl = t & 63, og = t >> 6;
  #pragma unroll
  for (int oi = 0; oi < 16; ++oi) {
    int o = og*16 + oi;
    float a = 0.f;
    #pragma unroll
    for (int cl = 0; cl < 8; ++cl) a += wgs[o*8 + cl] * xg_s[cl][kl];
    if (mbb == 0) a += bg[o];
    atomicAdd(out + ((size_t)(b*C4 + o))*NN + kb*64 + kl, a);
  }
}

extern "C" void kernel_launch(void* const* d_in, const int* in_sizes, int n_in,
                              void* d_out, int out_size, void* d_ws, size_t ws_size,
                              hipStream_t stream) {
  const float* x  = (const float*)d_in[0];
  const float* Wc = (const float*)d_in[1];
  const float* bc = (const float*)d_in[2];
  const float* Wg = (const float*)d_in[3];
  const float* bg = (const float*)d_in[4];
  float* ws  = (float*)d_ws;
  float* out = (float*)d_out;

  // no memsets: XX/YY replaced by fully-written partial arrays (k1a),
  // out zeroed by k12 before k3's atomics. 3 dispatches total.
  k1a_fc <<<B*64, 256, 0, stream>>>(x, Wc, bc, ws);
  k12_TS <<<B*64, 256, 0, stream>>>(x, ws, out);
  k3_mfma<<<B*64, 256, 0, stream>>>(Wg, bg, ws, out);
}

// Round 10
// 136.053 us; speedup vs baseline: 1.0289x; 1.0013x over previous
//
#include <hip/hip_runtime.h>
#include <hip/hip_bf16.h>
#include <math.h>

// Problem constants
#define B    8
#define C4   64
#define CQ   16
#define NN   512
#define L4   12
#define XSP  100          // padded LDS row stride for x (96 -> 100, bank fix)

// workspace layout (float offsets)
#define O_TH   0                                   // Thi bf16 [b][m][n]      2097152
#define O_TL   (O_TH + (size_t)B*1024*NN/2)        // Tlo bf16 [b][m][n]      2097152
#define O_FL   (O_TL + (size_t)B*1024*NN/2)        // Fl[b][q][k] fp32          65536
#define O_XXP  (O_FL + (size_t)B*CQ*NN)            // xx partials [b][q][nch]    8192
#define O_YYP  (O_XXP + (size_t)B*CQ*64)           // yy partials [b][q][nch]    8192
#define O_L2I  (O_YYP + (size_t)B*CQ*64)           // l2inv[b] (+pad to 16)        16
#define O_AH   (O_L2I + 16)                        // Ahi bf16 [b][n][k]      1048576
#define O_AL   (O_AH + (size_t)B*NN*NN/2)          // Alo bf16 [b][n][k]      1048576
#define O_FCG  (O_AL + (size_t)B*NN*NN/2)          // Fc scratch [blk][1536]   786432

// SESSION LEDGER:
//  r1: Fc-compute merged into T kernel -> VGPR=64 spill collapse. NO.
//  r2: k1t+k2 merge, T2 planes LDS-only: -5.5 us. YES.
//  r4: 4-row chunks / grid 1024: spill+RFO collapse. NO.
//  r6: k3 explicit double-buffer: neutral.
//  r7: dispatch elimination (memsets folded): -3 us. YES.
//  r8: FCG deletion via k12 recompute: +3.8 us. REVERTED.
//  r9 counters: k12 = 45 us, MfmaUtil 10%, VALUBusy 19%, occ 17.8%,
//     LDS 63.5 KB -> 2 blocks/CU. Latency-bound at low occupancy.
// This round: k12 LDS aliasing — t2 slabs overlay the dead xs/fcs region
// (phase-1 keeps T in registers; t2 written after a barrier). LDS 63.5->33 KB
// -> 4 blocks/CU. No change to per-thread work, decomposition, or k1a/k3.

typedef __attribute__((ext_vector_type(8))) short short8;
typedef __attribute__((ext_vector_type(4))) float floatx4;
typedef __attribute__((ext_vector_type(16))) float floatx16;

__device__ inline void split2(float x0, float x1, uint& hw, uint& lw) {
  uint u0 = __float_as_uint(x0), u1 = __float_as_uint(x1);
  uint h0 = u0 >> 16, h1 = u1 >> 16;
  float r0 = x0 - __uint_as_float(h0 << 16);
  float r1 = x1 - __uint_as_float(h1 << 16);
  hw = h0 | (h1 << 16);
  lw = (__float_as_uint(r0) >> 16) | ((__float_as_uint(r1) >> 16) << 16);
}

// K1a: Fc = Wc x + bc, Fl, norm PARTIALS; Fc -> global scratch. Unchanged.
__global__ __launch_bounds__(256) void k1a_fc(const float* __restrict__ x,
                                              const float* __restrict__ Wc,
                                              const float* __restrict__ bc,
                                              float* __restrict__ ws) {
  int id = blockIdx.x;
  int b = id & 7;
  int nch = id >> 3;
  int n0 = nch * 8;
  int t = threadIdx.x;
  __shared__ __align__(16) float xs[C4*XSP];       // [c][nl*12+j], padded
  __shared__ float wcs[CQ*65];
  __shared__ float bcs[CQ];
  __shared__ __align__(16) float fcs[8*CQ*L4];     // [nl][q][j] 1536

  for (int e = t; e < CQ*C4; e += 256) {
    int q = e >> 6, c = e & 63;
    wcs[q*65 + c] = Wc[e];
  }
  if (t < CQ) bcs[t] = bc[t];
  const float* xb = x + (size_t)b*C4*NN*L4 + (size_t)n0*L4;
  for (int f = t; f < C4*24; f += 256) {           // 24 float4s per c
    int c = f / 24, r = f - c*24;
    float4 v = *(const float4*)(xb + (size_t)c*NN*L4 + r*4);
    *(float4*)(xs + c*XSP + r*4) = v;
  }
  __syncthreads();
  // Fc: thread owns q = t&15, slots nj = (t>>4) + 16*i (i<6)
  {
    int q = t & 15, slot = t >> 4;
    float accv[6];
    #pragma unroll
    for (int i = 0; i < 6; ++i) accv[i] = bcs[q];
    for (int c = 0; c < C4; ++c) {
      float wv = wcs[q*65 + c];
      const float* xc = xs + c*XSP;
      #pragma unroll
      for (int i = 0; i < 6; ++i) accv[i] += wv * xc[slot + 16*i];
    }
    #pragma unroll
    for (int i = 0; i < 6; ++i) {
      int nj = slot + 16*i;
      int nl = nj / L4, j = nj - nl*L4;
      fcs[nl*(CQ*L4) + q*L4 + j] = accv[i];
      if (j == L4-1) ws[O_FL + ((size_t)b*CQ + q)*NN + n0 + nl] = accv[i];
    }
  }
  __syncthreads();
  if (t < CQ) {
    float yy = 0.f, xx = 0.f;
    for (int nl = 0; nl < 8; ++nl) {
      #pragma unroll
      for (int j = 0; j < L4; ++j) { float v = fcs[nl*(CQ*L4) + t*L4 + j]; yy += v*v; }
      float w = fcs[nl*(CQ*L4) + t*L4 + (L4-1)];
      xx += w*w;
    }
    ws[O_XXP + ((size_t)b*CQ + t)*64 + nch] = xx;
    ws[O_YYP + ((size_t)b*CQ + t)*64 + nch] = yy;
  }
  // dump Fc to global scratch (contiguous)
  float* fcg = ws + O_FCG + (size_t)(b*64 + nch)*1536;
  for (int f = t; f < 384; f += 256)
    *(float4*)(fcg + f*4) = *(const float4*)(fcs + f*4);
}

// K12: phase 1 computes T into REGISTERS (vals) from xs/fcs; TH/TL written
// to global. After a barrier, the t2 slabs are written into LDS ALIASED over
// the now-dead xs/fcs region; phase 2 runs pass-1 MFMA on them.
// LDS 63.5 KB -> ~33 KB => 4 blocks/CU (was 2). Data stored is bit-identical.
__global__ __launch_bounds__(256, 2) void k12_TS(const float* __restrict__ x,
                                                 float* __restrict__ ws,
                                                 float* __restrict__ out) {
  int id = blockIdx.x;
  int b = id & 7;
  int nch = id >> 3;
  int n0 = nch * 8;
  int t = threadIdx.x;
  // one aliased arena: phase A = xs(25600 B) + fcs(6144 B) = 31744 B
  //                    phase B = t2h(16384 B) + t2l(16384 B) = 32768 B
  __shared__ __align__(16) char smem[32768];
  float*  xs  = (float*)smem;                      // [c][nl*12+j], XSP stride
  float*  fcs = (float*)(smem + 25600);            // [nl][q][j]
  ushort* t2h = (ushort*)smem;                     // [nl][m]
  ushort* t2l = (ushort*)(smem + 16384);           // [nl][m]
  __shared__ float l2tmp[CQ];                      // persists across phases

  // zero the output slice (2 KB/block) — replaces the memset dispatch
  if (t < 128) {
    float4 z = make_float4(0.f, 0.f, 0.f, 0.f);
    *(float4*)(out + (size_t)id*512 + t*4) = z;
  }
  const float* xb = x + (size_t)b*C4*NN*L4 + (size_t)n0*L4;
  for (int f = t; f < C4*24; f += 256) {
    int c = f / 24, r = f - c*24;
    float4 v = *(const float4*)(xb + (size_t)c*NN*L4 + r*4);
    *(float4*)(xs + c*XSP + r*4) = v;
  }
  {
    const float* fcg = ws + O_FCG + (size_t)(b*64 + nch)*1536;
    for (int f = t; f < 384; f += 256)
      *(float4*)(fcs + f*4) = *(const float4*)(fcg + f*4);
  }
  if (t < CQ) {
    const float* xp = ws + O_XXP + ((size_t)b*CQ + t)*64;
    const float* yp = ws + O_YYP + ((size_t)b*CQ + t)*64;
    float sx = 0.f, sy = 0.f;
    for (int j = 0; j < 64; ++j) { sx += xp[j]; sy += yp[j]; }
    l2tmp[t] = sqrtf(sx) * sqrtf(sy);
  }
  __syncthreads();

  // ---- phase 1: T values into registers (identical math) ----
  int c = t >> 2, q0 = (t & 3) * 4;
  float vals[4][8];
  for (int nl = 0; nl < 8; ++nl) {
    float xr[L4];
    *(float4*)&xr[0] = *(const float4*)(xs + c*XSP + nl*L4);
    *(float4*)&xr[4] = *(const float4*)(xs + c*XSP + nl*L4 + 4);
    *(float4*)&xr[8] = *(const float4*)(xs + c*XSP + nl*L4 + 8);
    #pragma unroll
    for (int i = 0; i < 4; ++i) {
      const float* fq = fcs + nl*(CQ*L4) + (q0+i)*L4;
      float a = 0.f;
      #pragma unroll
      for (int j = 0; j < L4; ++j) a += fq[j] * xr[j];
      vals[i][nl] = a;
    }
  }
  // TH/TL global writes (no LDS involved)
  ushort* TH = (ushort*)(ws + O_TH);
  ushort* TL = (ushort*)(ws + O_TL);
  #pragma unroll
  for (int i = 0; i < 4; ++i) {
    int m = c*16 + q0 + i;
    uint hw[4], lw[4];
    #pragma unroll
    for (int jj = 0; jj < 4; ++jj)
      split2(vals[i][2*jj], vals[i][2*jj+1], hw[jj], lw[jj]);
    size_t off = ((size_t)b*1024 + m)*NN + n0;
    *(uint4*)(TH + off) = make_uint4(hw[0], hw[1], hw[2], hw[3]);
    *(uint4*)(TL + off) = make_uint4(lw[0], lw[1], lw[2], lw[3]);
  }
  __syncthreads();            // all xs/fcs reads done — arena reusable

  // ---- phase 1b: t2 slabs from registers into aliased LDS ----
  #pragma unroll
  for (int nl = 0; nl < 8; ++nl) {
    uint hw0, lw0, hw1, lw1;
    split2(vals[0][nl], vals[1][nl], hw0, lw0);
    split2(vals[2][nl], vals[3][nl], hw1, lw1);
    *(uint2*)(t2h + nl*1024 + t*4) = make_uint2(hw0, hw1);
    *(uint2*)(t2l + nl*1024 + t*4) = make_uint2(lw0, lw1);
  }
  __syncthreads();

  // ---- phase 2: pass-1 MFMA over the LDS T2 slab ----
  float l2sum = 0.f;
  #pragma unroll
  for (int q = 0; q < CQ; ++q) l2sum += l2tmp[q];
  float l2inv = 1.0f / l2sum;
  if (nch == 0 && t == 0) ws[O_L2I + b] = l2inv;   // publish for k3

  int w = t >> 6, lane = t & 63;
  int col = lane & 31, half = lane >> 5;
  const float* flb = ws + O_FL + (size_t)b*CQ*NN;
  short8 bhf[4], blf[4];
  int kcol[4];
  #pragma unroll
  for (int kt = 0; kt < 4; ++kt) {
    kcol[kt] = w*128 + kt*32 + col;
    float f[8];
    #pragma unroll
    for (int e = 0; e < 8; ++e) f[e] = flb[(size_t)(half*8 + e)*NN + kcol[kt]];
    #pragma unroll
    for (int p = 0; p < 4; ++p) {
      uint hw, lw;
      split2(f[2*p], f[2*p+1], hw, lw);
      ((uint*)&bhf[kt])[p] = hw;
      ((uint*)&blf[kt])[p] = lw;
    }
  }
  ushort* AH = (ushort*)(ws + O_AH) + ((size_t)b*NN + n0)*NN;
  ushort* AL = (ushort*)(ws + O_AL) + ((size_t)b*NN + n0)*NN;

  for (int i = 0; i < 8; ++i) {
    short8 ah[2], al[2];
    #pragma unroll
    for (int ct = 0; ct < 2; ++ct) {
      int off = i*1024 + (ct*32 + col)*16 + half*8;
      ah[ct] = *(const short8*)(t2h + off);
      al[ct] = *(const short8*)(t2l + off);
    }
    #pragma unroll
    for (int kt = 0; kt < 4; ++kt) {
      floatx16 acc[2];
      #pragma unroll
      for (int ct = 0; ct < 2; ++ct) {
        floatx16 a = {0.f,0.f,0.f,0.f,0.f,0.f,0.f,0.f,
                      0.f,0.f,0.f,0.f,0.f,0.f,0.f,0.f};
        a = __builtin_amdgcn_mfma_f32_32x32x16_bf16(ah[ct], bhf[kt], a, 0, 0, 0);
        a = __builtin_amdgcn_mfma_f32_32x32x16_bf16(ah[ct], blf[kt], a, 0, 0, 0);
        a = __builtin_amdgcn_mfma_f32_32x32x16_bf16(al[ct], bhf[kt], a, 0, 0, 0);
        acc[ct] = a;
      }
      float m = acc[0][0];
      #pragma unroll
      for (int ct = 0; ct < 2; ++ct)
        #pragma unroll
        for (int rg = 0; rg < 16; ++rg)
          if (ct + rg) m = fmaxf(m, acc[ct][rg]);
      m = fmaxf(m, __shfl_xor(m, 32));
      // relu(tanh(x)) == tanh(relu(x)); tanh(x>=0) = 1 - 2/(e^{2x}+1)
      float xp = fmaxf(m * l2inv, 0.f);
      float av = 1.f - __fdividef(2.f, __expf(2.f * xp) + 1.f);
      uint u = __float_as_uint(av);
      uint hh = u >> 16;
      float r = av - __uint_as_float(hh << 16);
      ushort lv = (ushort)(__float_as_uint(r) >> 16);
      if (half == 0) {
        AH[(size_t)i*NN + kcol[kt]] = (ushort)hh;
        AL[(size_t)i*NN + kcol[kt]] = lv;
      }
    }
  }
}

// K3 (pass 2, MFMA split-bf16) with fused output GEMM. Unchanged.
__global__ __launch_bounds__(256, 2) void k3_mfma(const float* __restrict__ Wg,
                                                  const float* __restrict__ bg,
                                                  float* __restrict__ ws,
                                                  float* __restrict__ out) {
  int id = blockIdx.x;             // (mbb*8 + kb)*8 + b
  int b = id & 7;
  int rest = id >> 3;
  int kb = rest & 7;
  int mbb = rest >> 3;
  int t = threadIdx.x;
  int lane = t & 63;
  int w = t >> 6;
  int mw = w >> 1, kw = w & 1;
  int row = lane & 15, quad = lane >> 4;

  __shared__ __align__(16) ushort Ah[2][128*32];   // 16 KB
  __shared__ __align__(16) ushort Al[2][128*32];   // 16 KB
  __shared__ __align__(16) ushort Bh[2][64*32];    // 8 KB
  __shared__ __align__(16) ushort Bl[2][64*32];    // 8 KB
  __shared__ float wgs[C4*8];       // Wg[o][c-slice]
  __shared__ float xg_s[8][64];     // xg slice [c-local][k-local]

  float l2inv = ws[O_L2I + b];
  for (int e = t; e < C4*8; e += 256) {
    int o = e >> 3, cl = e & 7;
    wgs[e] = Wg[o*C4 + mbb*8 + cl];
  }

  const ushort* TH = (const ushort*)(ws + O_TH) + ((size_t)b*1024 + mbb*128)*NN;
  const ushort* TL = (const ushort*)(ws + O_TL) + ((size_t)b*1024 + mbb*128)*NN;
  const ushort* AHp = (const ushort*)(ws + O_AH) + ((size_t)b*NN + kb*64)*NN;
  const ushort* ALp = (const ushort*)(ws + O_AL) + ((size_t)b*NN + kb*64)*NN;

  // staging geometry: lds ushort offset f*8 == (f>>2)*32 + (f&3)*8 (linear)
  const int mA0 = t >> 2,        sA0 = (t & 3) * 8;
  const int mA1 = (t + 256) >> 2, sA1 = (t & 3) * 8;   // (t+256)&3 == t&3
  const int jB  = t >> 2,        sB  = (t & 3) * 8;

  uint4 rah0, rah1, ral0, ral1, rbh, rbl;              // named regs (no arrays)
  #define K3_LOAD(p0)                                                    \
    rah0 = *(const uint4*)(TH + (size_t)mA0*NN + (p0) + sA0);            \
    rah1 = *(const uint4*)(TH + (size_t)mA1*NN + (p0) + sA1);            \
    ral0 = *(const uint4*)(TL + (size_t)mA0*NN + (p0) + sA0);            \
    ral1 = *(const uint4*)(TL + (size_t)mA1*NN + (p0) + sA1);            \
    rbh  = *(const uint4*)(AHp + (size_t)jB*NN + (p0) + sB);             \
    rbl  = *(const uint4*)(ALp + (size_t)jB*NN + (p0) + sB);
  #define K3_WRITE(buf)                                                  \
    *(uint4*)(&Ah[buf][t*8])         = rah0;                             \
    *(uint4*)(&Ah[buf][(t+256)*8])   = rah1;                             \
    *(uint4*)(&Al[buf][t*8])         = ral0;                             \
    *(uint4*)(&Al[buf][(t+256)*8])   = ral1;                             \
    *(uint4*)(&Bh[buf][t*8])         = rbh;                              \
    *(uint4*)(&Bl[buf][t*8])         = rbl;

  floatx4 acc[4][2];
  #pragma unroll
  for (int i = 0; i < 4; ++i)
    #pragma unroll
    for (int j = 0; j < 2; ++j) acc[i][j] = (floatx4){0.f, 0.f, 0.f, 0.f};

  // prologue: stage tile 0 into buffer 0
  K3_LOAD(0)
  K3_WRITE(0)
  __syncthreads();

  int cur = 0;
  for (int ksx = 0; ksx < 16; ++ksx) {
    if (ksx < 15) { K3_LOAD((ksx+1)*32) }   // issue next-tile loads early
    // compute tile ksx from buf[cur]
    short8 bh[2], bl[2];
    #pragma unroll
    for (int kt = 0; kt < 2; ++kt) {
      int jrow = kw*32 + kt*16 + row;
      bh[kt] = *(const short8*)(&Bh[cur][jrow*32 + quad*8]);
      bl[kt] = *(const short8*)(&Bl[cur][jrow*32 + quad*8]);
    }
    #pragma unroll
    for (int mt = 0; mt < 4; ++mt) {
      int mrow = mw*64 + mt*16 + row;
      short8 ah = *(const short8*)(&Ah[cur][mrow*32 + quad*8]);
      short8 al = *(const short8*)(&Al[cur][mrow*32 + quad*8]);
      #pragma unroll
      for (int kt = 0; kt < 2; ++kt) {
        acc[mt][kt] = __builtin_amdgcn_mfma_f32_16x16x32_bf16(ah, bh[kt], acc[mt][kt], 0, 0, 0);
        acc[mt][kt] = __builtin_amdgcn_mfma_f32_16x16x32_bf16(ah, bl[kt], acc[mt][kt], 0, 0, 0);
        acc[mt][kt] = __builtin_amdgcn_mfma_f32_16x16x32_bf16(al, bh[kt], acc[mt][kt], 0, 0, 0);
      }
    }
    if (ksx < 15) {
      K3_WRITE(cur ^ 1)       // load latency was hidden under the MFMAs above
      __syncthreads();        // single barrier per K-step
      cur ^= 1;
    }
  }

  const float* flb = ws + O_FL + (size_t)b*CQ*NN;
  float fl[2][4];
  #pragma unroll
  for (int kt = 0; kt < 2; ++kt) {
    int kcol = kb*64 + kw*32 + kt*16 + row;
    #pragma unroll
    for (int rg = 0; rg < 4; ++rg)
      fl[kt][rg] = flb[(size_t)(quad*4 + rg)*NN + kcol];
  }
  #pragma unroll
  for (int mt = 0; mt < 4; ++mt) {
    #pragma unroll
    for (int kt = 0; kt < 2; ++kt) {
      float s = fl[kt][0]*acc[mt][kt][0] + fl[kt][1]*acc[mt][kt][1]
              + fl[kt][2]*acc[mt][kt][2] + fl[kt][3]*acc[mt][kt][3];
      s += __shfl_xor(s, 32);
      s += __shfl_xor(s, 16);
      if (quad == 0)
        xg_s[mw*4 + mt][kw*32 + kt*16 + row] = s * l2inv;
    }
  }
  __syncthreads();
  // mini-GEMM: Fg partial = Wg[:, c-slice] * xg_s, atomic into out
  int kl = t & 63, og = t >> 6;
  #pragma unroll
  for (int oi = 0; oi < 16; ++oi) {
    int o = og*16 + oi;
    float a = 0.f;
    #pragma unroll
    for (int cl = 0; cl < 8; ++cl) a += wgs[o*8 + cl] * xg_s[cl][kl];
    if (mbb == 0) a += bg[o];
    atomicAdd(out + ((size_t)(b*C4 + o))*NN + kb*64 + kl, a);
  }
}

extern "C" void kernel_launch(void* const* d_in, const int* in_sizes, int n_in,
                              void* d_out, int out_size, void* d_ws, size_t ws_size,
                              hipStream_t stream) {
  const float* x  = (const float*)d_in[0];
  const float* Wc = (const float*)d_in[1];
  const float* bc = (const float*)d_in[2];
  const float* Wg = (const float*)d_in[3];
  const float* bg = (const float*)d_in[4];
  float* ws  = (float*)d_ws;
  float* out = (float*)d_out;

  // 3 dispatches, no memsets.
  k1a_fc <<<B*64, 256, 0, stream>>>(x, Wc, bc, ws);
  k12_TS <<<B*64, 256, 0, stream>>>(x, ws, out);
  k3_mfma<<<B*64, 256, 0, stream>>>(Wg, bg, ws, out);
}